// Round 1
// baseline (16711.613 us; speedup 1.0000x reference)
//
#include <hip/hip_runtime.h>
#include <math.h>

#define B_  32
#define S_  64
#define T_  48
#define V_  32000
#define E_  512
#define H_  1024
#define G3  3072   // 3*H

// ---------------------------------------------------------------------------
// Generic tiled f32 GEMM:  C[m][n] = sum_k A[m][k] * W[n][k]  (+ bias[n])
// A rows optionally gathered through an id table (embedding lookup).
// out_mode 0: C[m*ldc + n]
// out_mode 1: m = t*32+b -> C[b*(47*V) + t*V + n], rows m>=M skipped
// Grid: (N/64, ceil(M/64)), block 256. K multiple of 32, N multiple of 64.
// ---------------------------------------------------------------------------
__global__ __launch_bounds__(256)
void gemm_bt(const float* __restrict__ A, int lda,
             const int* __restrict__ ids, int id_mode,  // 0 none, 1 enc b*64+t, 2 dec b*48+t
             const float* __restrict__ W, int ldw,
             const float* __restrict__ bias,
             float* __restrict__ C, int out_mode, int ldc,
             int M, int K)
{
    __shared__ __align__(16) float As[32][68];  // [k][m], pad 68 for bank spread
    __shared__ __align__(16) float Ws[32][68];  // [k][n]
    const int tid  = threadIdx.x;
    const int n0   = blockIdx.x * 64;
    const int m0   = blockIdx.y * 64;
    const int srow = tid >> 2;          // 0..63 staging row
    const int kq   = (tid & 3) * 8;     // 0,8,16,24

    long abase;
    {
        int m = m0 + srow;
        if (id_mode == 0) {
            abase = (long)m * lda;
        } else {
            int t = m >> 5, b = m & 31;
            int idx = (id_mode == 1) ? (b * S_ + t) : (b * T_ + t);
            abase = (long)ids[idx] * lda;
        }
    }
    const float* Ar = A + abase;
    const float* Wr = W + (long)(n0 + srow) * ldw;

    const int tx = (tid & 15) * 4;   // n offset
    const int ty = (tid >> 4) * 4;   // m offset
    float acc[4][4] = {};

    for (int k0 = 0; k0 < K; k0 += 32) {
        float4 a0 = *(const float4*)(Ar + k0 + kq);
        float4 a1 = *(const float4*)(Ar + k0 + kq + 4);
        float4 w0 = *(const float4*)(Wr + k0 + kq);
        float4 w1 = *(const float4*)(Wr + k0 + kq + 4);
        __syncthreads();   // previous iteration's reads complete
        As[kq+0][srow]=a0.x; As[kq+1][srow]=a0.y; As[kq+2][srow]=a0.z; As[kq+3][srow]=a0.w;
        As[kq+4][srow]=a1.x; As[kq+5][srow]=a1.y; As[kq+6][srow]=a1.z; As[kq+7][srow]=a1.w;
        Ws[kq+0][srow]=w0.x; Ws[kq+1][srow]=w0.y; Ws[kq+2][srow]=w0.z; Ws[kq+3][srow]=w0.w;
        Ws[kq+4][srow]=w1.x; Ws[kq+5][srow]=w1.y; Ws[kq+6][srow]=w1.z; Ws[kq+7][srow]=w1.w;
        __syncthreads();
#pragma unroll
        for (int k = 0; k < 32; ++k) {
            float4 av = *(const float4*)&As[k][ty];
            float4 wv = *(const float4*)&Ws[k][tx];
            acc[0][0] += av.x*wv.x; acc[0][1] += av.x*wv.y; acc[0][2] += av.x*wv.z; acc[0][3] += av.x*wv.w;
            acc[1][0] += av.y*wv.x; acc[1][1] += av.y*wv.y; acc[1][2] += av.y*wv.z; acc[1][3] += av.y*wv.w;
            acc[2][0] += av.z*wv.x; acc[2][1] += av.z*wv.y; acc[2][2] += av.z*wv.z; acc[2][3] += av.z*wv.w;
            acc[3][0] += av.w*wv.x; acc[3][1] += av.w*wv.y; acc[3][2] += av.w*wv.z; acc[3][3] += av.w*wv.w;
        }
    }

    float4 bv = make_float4(0.f, 0.f, 0.f, 0.f);
    if (bias) bv = *(const float4*)(bias + n0 + tx);
#pragma unroll
    for (int i = 0; i < 4; ++i) {
        int m = m0 + ty + i;
        float4 o;
        o.x = acc[i][0] + bv.x; o.y = acc[i][1] + bv.y;
        o.z = acc[i][2] + bv.z; o.w = acc[i][3] + bv.w;
        if (out_mode == 0) {
            *(float4*)(C + (long)m * ldc + n0 + tx) = o;
        } else if (m < M) {
            int t = m >> 5, b = m & 31;
            *(float4*)(C + (long)b * ((T_-1)*V_) + (long)t * V_ + n0 + tx) = o;
        }
    }
}

// ---------------------------------------------------------------------------
// Fused GRU step: for output unit j (block), compute over all 32 batch rows:
//   gh = h @ whh.T + bhh ;  gi = [gi_pre] + [x @ wx.T (+bih)]
//   r=sig(gi_r+gh_r) z=sig(gi_z+gh_z) n=tanh(gi_n + r*gh_n)
//   h' = (1-z)*n + z*h
// Block: 256 thr = (b 0..31) x (ks 0..7, K-slice of 128). Grid: 1024 (j).
// W rows are read with wave-broadcast addresses (same addr across b lanes).
// ---------------------------------------------------------------------------
template<int HAS_X, int HAS_GI>
__global__ __launch_bounds__(256)
void gru_layer(const float* __restrict__ x, int xld,
               const float* __restrict__ wx, int wxld, int wxoff,
               const float* __restrict__ bih,
               const float* __restrict__ gi_pre,   // row stride G3, rows = b (bias included)
               const float* __restrict__ h,
               const float* __restrict__ whh,
               const float* __restrict__ bhh,
               float* __restrict__ h_new,
               float* __restrict__ seq_out, long seq_stride)
{
    const int j   = blockIdx.x;
    const int tid = threadIdx.x;
    const int b   = tid & 31;
    const int ks  = tid >> 5;
    __shared__ float redh[3][8][32];
    __shared__ float redx[3][8][32];

    const float* hr = h + (long)b * H_;
    const float* w0 = whh + (long)j * H_;
    const float* w1 = whh + (long)(H_ + j) * H_;
    const float* w2 = whh + (long)(2*H_ + j) * H_;
    const float* xr = nullptr; const float *u0 = nullptr, *u1 = nullptr, *u2 = nullptr;
    if (HAS_X) {
        xr = x + (long)b * xld;
        u0 = wx + (long)j * wxld + wxoff;
        u1 = wx + (long)(H_ + j) * wxld + wxoff;
        u2 = wx + (long)(2*H_ + j) * wxld + wxoff;
    }
    float ah0 = 0.f, ah1 = 0.f, ah2 = 0.f;
    float ax0 = 0.f, ax1 = 0.f, ax2 = 0.f;
    const int k0 = ks * 128;
#pragma unroll 4
    for (int k = k0; k < k0 + 128; k += 4) {
        float4 hv = *(const float4*)(hr + k);
        float4 p  = *(const float4*)(w0 + k);
        float4 q  = *(const float4*)(w1 + k);
        float4 rr = *(const float4*)(w2 + k);
        ah0 += hv.x*p.x  + hv.y*p.y  + hv.z*p.z  + hv.w*p.w;
        ah1 += hv.x*q.x  + hv.y*q.y  + hv.z*q.z  + hv.w*q.w;
        ah2 += hv.x*rr.x + hv.y*rr.y + hv.z*rr.z + hv.w*rr.w;
        if (HAS_X) {
            float4 xv = *(const float4*)(xr + k);
            float4 e  = *(const float4*)(u0 + k);
            float4 f  = *(const float4*)(u1 + k);
            float4 g  = *(const float4*)(u2 + k);
            ax0 += xv.x*e.x + xv.y*e.y + xv.z*e.z + xv.w*e.w;
            ax1 += xv.x*f.x + xv.y*f.y + xv.z*f.z + xv.w*f.w;
            ax2 += xv.x*g.x + xv.y*g.y + xv.z*g.z + xv.w*g.w;
        }
    }
    redh[0][ks][b] = ah0; redh[1][ks][b] = ah1; redh[2][ks][b] = ah2;
    if (HAS_X) { redx[0][ks][b] = ax0; redx[1][ks][b] = ax1; redx[2][ks][b] = ax2; }
    __syncthreads();
    if (tid < 32) {
        const int bb = tid;
        float gh0 = bhh[j], gh1 = bhh[H_ + j], gh2 = bhh[2*H_ + j];
#pragma unroll
        for (int q = 0; q < 8; ++q) {
            gh0 += redh[0][q][bb]; gh1 += redh[1][q][bb]; gh2 += redh[2][q][bb];
        }
        float gi0, gi1, gi2;
        if (HAS_GI) {
            const float* g = gi_pre + (long)bb * G3;
            gi0 = g[j]; gi1 = g[H_ + j]; gi2 = g[2*H_ + j];
        } else {
            gi0 = bih[j]; gi1 = bih[H_ + j]; gi2 = bih[2*H_ + j];
        }
        if (HAS_X) {
#pragma unroll
            for (int q = 0; q < 8; ++q) {
                gi0 += redx[0][q][bb]; gi1 += redx[1][q][bb]; gi2 += redx[2][q][bb];
            }
        }
        float r = 1.f / (1.f + expf(-(gi0 + gh0)));
        float z = 1.f / (1.f + expf(-(gi1 + gh1)));
        float n = tanhf(gi2 + r * gh2);
        float hv = h[(long)bb * H_ + j];
        float o = (1.f - z) * n + z * hv;
        h_new[(long)bb * H_ + j] = o;
        if (seq_out) seq_out[(long)bb * seq_stride + j] = o;
    }
}

// ---------------------------------------------------------------------------
// Attention for one decoder step. Grid: 32 (b). Block: 256.
// score[s] = proj[b][s][:] . d1[b][:]  (masked), softmax, ctx = attn @ enc_out
// ctx written to ctx_out + b*2048 (second half of cat row).
// ---------------------------------------------------------------------------
__global__ __launch_bounds__(256)
void attention_kernel(const float* __restrict__ proj,
                      const float* __restrict__ enc_out,
                      const int* __restrict__ src_ids,
                      const float* __restrict__ d1,
                      float* __restrict__ ctx_out)
{
    const int b = blockIdx.x;
    const int tid = threadIdx.x;
    __shared__ __align__(16) float dl[H_];
    __shared__ float attn[S_];

    *(float4*)&dl[tid * 4] = *(const float4*)(d1 + (long)b * H_ + tid * 4);
    __syncthreads();

    const int lane = tid & 63, wid = tid >> 6;
    for (int s = wid; s < S_; s += 4) {
        const float* pr = proj + ((long)b * S_ + s) * H_;
        float a = 0.f;
#pragma unroll
        for (int c = 0; c < 4; ++c) {
            float4 pv = *(const float4*)(pr + c * 256 + lane * 4);
            float4 dv = *(const float4*)&dl[c * 256 + lane * 4];
            a += pv.x*dv.x + pv.y*dv.y + pv.z*dv.z + pv.w*dv.w;
        }
#pragma unroll
        for (int off = 32; off > 0; off >>= 1) a += __shfl_xor(a, off);
        if (lane == 0) attn[s] = (src_ids[b * S_ + s] != 0) ? a : -1e9f;
    }
    __syncthreads();
    if (tid < 64) {
        float v = attn[tid];
        float mx = v;
#pragma unroll
        for (int off = 32; off > 0; off >>= 1) mx = fmaxf(mx, __shfl_xor(mx, off));
        float e = expf(v - mx);
        float sm = e;
#pragma unroll
        for (int off = 32; off > 0; off >>= 1) sm += __shfl_xor(sm, off);
        attn[tid] = e / sm;
    }
    __syncthreads();
    float4 acc = make_float4(0.f, 0.f, 0.f, 0.f);
    const float* eb = enc_out + (long)b * S_ * H_ + tid * 4;
    for (int s = 0; s < S_; ++s) {
        float w = attn[s];
        float4 ev = *(const float4*)(eb + (long)s * H_);
        acc.x += w * ev.x; acc.y += w * ev.y; acc.z += w * ev.z; acc.w += w * ev.w;
    }
    *(float4*)(ctx_out + (long)b * 2048 + tid * 4) = acc;
}

// ---------------------------------------------------------------------------
extern "C" void kernel_launch(void* const* d_in, const int* in_sizes, int n_in,
                              void* d_out, int out_size, void* d_ws, size_t ws_size,
                              hipStream_t stream)
{
    (void)in_sizes; (void)n_in; (void)out_size; (void)ws_size;
    const int*   src_ids  = (const int*)  d_in[0];
    const int*   tgt_ids  = (const int*)  d_in[2];
    const float* enc_emb  = (const float*)d_in[3];
    const float* dec_emb  = (const float*)d_in[4];
    const float* enc_wih0 = (const float*)d_in[5];
    const float* enc_whh0 = (const float*)d_in[6];
    const float* enc_bih0 = (const float*)d_in[7];
    const float* enc_bhh0 = (const float*)d_in[8];
    const float* enc_wih1 = (const float*)d_in[9];
    const float* enc_whh1 = (const float*)d_in[10];
    const float* enc_bih1 = (const float*)d_in[11];
    const float* enc_bhh1 = (const float*)d_in[12];
    const float* dec_wih0 = (const float*)d_in[13];
    const float* dec_whh0 = (const float*)d_in[14];
    const float* dec_bih0 = (const float*)d_in[15];
    const float* dec_bhh0 = (const float*)d_in[16];
    const float* dec_wih1 = (const float*)d_in[17];
    const float* dec_whh1 = (const float*)d_in[18];
    const float* dec_bih1 = (const float*)d_in[19];
    const float* dec_bhh1 = (const float*)d_in[20];
    const float* attn_w   = (const float*)d_in[21];
    const float* out_w    = (const float*)d_in[22];
    const float* out_b    = (const float*)d_in[23];
    float* out = (float*)d_out;

    // workspace layout (floats)
    float* ws      = (float*)d_ws;
    float* gi_enc0 = ws;                         // 2048*3072
    float* gi_dec  = gi_enc0 + 2048L * G3;       // 1536*3072
    float* enc_out = gi_dec  + 1536L * G3;       // 2048*1024  [b][t][h]
    float* proj    = enc_out + 2048L * H_;       // 2048*1024  [b][s][h]
    float* cat     = proj    + 2048L * H_;       // 1536*2048  row m=t*32+b: [d1 | ctx]
    float* states  = cat     + 1536L * 2048;     // 4*32*1024
    float* h0[2] = { states,             states + 1L*B_*H_ };
    float* h1[2] = { states + 2L*B_*H_,  states + 3L*B_*H_ };

    hipMemsetAsync(states, 0, 4L * B_ * H_ * sizeof(float), stream);

    // batched input-to-hidden GEMMs (embedding gather fused)
    gemm_bt<<<dim3(48, 32), 256, 0, stream>>>(enc_emb, E_, src_ids, 1, enc_wih0, E_, enc_bih0,
                                              gi_enc0, 0, G3, 2048, E_);
    gemm_bt<<<dim3(48, 24), 256, 0, stream>>>(dec_emb, E_, tgt_ids, 2, dec_wih0, E_ + H_, dec_bih0,
                                              gi_dec, 0, G3, 1536, E_);

    // ---- encoder ----
    int p = 0;
    for (int t = 0; t < S_; ++t) {
        gru_layer<0, 1><<<H_, 256, 0, stream>>>(
            nullptr, 0, nullptr, 0, 0, nullptr,
            gi_enc0 + (long)t * B_ * G3, h0[p], enc_whh0, enc_bhh0,
            h0[1 - p], nullptr, 0);
        gru_layer<1, 0><<<H_, 256, 0, stream>>>(
            h0[1 - p], H_, enc_wih1, H_, 0, enc_bih1, nullptr,
            h1[p], enc_whh1, enc_bhh1,
            h1[1 - p], enc_out + (long)t * H_, (long)S_ * H_);
        p ^= 1;
    }
    // p == 0 again after 64 steps; enc final states in h0[0], h1[0]

    // proj = enc_out @ attn_w.T   (M=2048, N=1024, K=1024)
    gemm_bt<<<dim3(16, 32), 256, 0, stream>>>(enc_out, H_, nullptr, 0, attn_w, H_, nullptr,
                                              proj, 0, H_, 2048, H_);

    // ---- decoder ----
    for (int t = 0; t < T_ - 1; ++t) {
        attention_kernel<<<B_, 256, 0, stream>>>(proj, enc_out, src_ids, h1[p],
                                                 cat + (long)t * B_ * 2048 + H_);
        gru_layer<1, 1><<<H_, 256, 0, stream>>>(
            cat + (long)t * B_ * 2048 + H_, 2048,       // x = ctx
            dec_wih0, E_ + H_, E_,                      // ctx columns of wih0
            nullptr, gi_dec + (long)t * B_ * G3,
            h0[p], dec_whh0, dec_bhh0,
            h0[1 - p], nullptr, 0);
        gru_layer<1, 0><<<H_, 256, 0, stream>>>(
            h0[1 - p], H_, dec_wih1, H_, 0, dec_bih1, nullptr,
            h1[p], dec_whh1, dec_bhh1,
            h1[1 - p], cat + (long)t * B_ * 2048, 2048);
        p ^= 1;
    }

    // ---- output projection: out = cat @ out_w.T + out_b ----
    gemm_bt<<<dim3(V_ / 64, 24), 256, 0, stream>>>(cat, 2048, nullptr, 0, out_w, 2048, out_b,
                                                   out, 1, 0, 1504, 2048);
}